// Round 14
// baseline (116.693 us; speedup 1.0000x reference)
//
#include <hip/hip_runtime.h>
#include <hip/hip_bf16.h>

typedef __attribute__((ext_vector_type(4))) float f32x4;
typedef __attribute__((ext_vector_type(8))) short bf16x8;

#define SDIM 256
#define HID 1024
#define ADIM 64
#define CHUNK 16
#define NCHUNK 128
#define NCH 32768  // BATCH * HID

// tier-1 (fp8 bbuf, no states copy): bbuf8 [0,64M); SC [64M,80M); bwb; cwb
#define WS8_SCB  67108864ull
#define WS8_BWB  83886080ull
#define WS8_CWB  84410368ull
#define WS8_NEED 84541440ull
// tier-2 (round-7 proven, bf16 bbuf at 0, stb at 128M)
#define WS_STB2  134217728ull
#define WS_SBUF2 134217728ull
#define WS_CBUF2 150994944ull
#define WS_BWB2  167772160ull
#define WS_CWB2  168296448ull
#define WS_NEED2 168427520ull

__device__ __forceinline__ unsigned short f2bf(float f) {
  unsigned int u = __float_as_uint(f);
  u += 0x7FFF + ((u >> 16) & 1);  // RNE
  return (unsigned short)(u >> 16);
}
__device__ __forceinline__ float bf2f(unsigned short h) {
  return __uint_as_float(((unsigned int)h) << 16);
}
// pure (non-volatile): CSE-able, freely schedulable
__device__ __forceinline__ float fast_exp2(float x) {
  float r;
  asm("v_exp_f32 %0, %1" : "=v"(r) : "v"(x));
  return r;
}
__device__ __forceinline__ float fast_rcp(float x) {
  float r;
  asm("v_rcp_f32 %0, %1" : "=v"(r) : "v"(x));
  return r;
}
// pack 2 fp32 -> 2 bf16 (RNE), single HW instr (T12 primitive)
__device__ __forceinline__ unsigned int cvt_pk_bf16(float lo, float hi) {
  unsigned int r;
  asm("v_cvt_pk_bf16_f32 %0, %1, %2" : "=v"(r) : "v"(lo), "v"(hi));
  return r;
}
#define LOG2E 1.4426950408889634f

#define GLDS16(gp, lp)                                                        \
  __builtin_amdgcn_global_load_lds(                                           \
      (const __attribute__((address_space(1))) unsigned int*)(gp),            \
      (__attribute__((address_space(3))) unsigned int*)(lp), 16, 0, 0)

// ---------------- tier-1: convert only B_w, C_w (tiny) ---------------------
#define CVTW_BN 262144
__global__ __launch_bounds__(256) void k_cvt_w(
    const float* __restrict__ bw, const float* __restrict__ cw,
    unsigned short* __restrict__ bwb, unsigned short* __restrict__ cwb) {
  long long f = ((long long)blockIdx.x * 256 + threadIdx.x) * 8;
  const float* src;
  unsigned short* dst;
  long long idx;
  if (f < CVTW_BN) { src = bw; dst = bwb; idx = f; }
  else { src = cw; dst = cwb; idx = f - CVTW_BN; }
  float4 a = *reinterpret_cast<const float4*>(src + idx);
  float4 b = *reinterpret_cast<const float4*>(src + idx + 4);
  ushort4 lo, hi;
  lo.x = f2bf(a.x); lo.y = f2bf(a.y); lo.z = f2bf(a.z); lo.w = f2bf(a.w);
  hi.x = f2bf(b.x); hi.y = f2bf(b.y); hi.z = f2bf(b.z); hi.w = f2bf(b.w);
  *reinterpret_cast<ushort4*>(dst + idx) = lo;
  *reinterpret_cast<ushort4*>(dst + idx + 4) = hi;
}

// ---------------- tier-2: full pre-convert (states, B_w, C_w) --------------
#define CVT_SN 16777216
#define CVT_BN 262144
__global__ __launch_bounds__(256) void k_cvt(
    const float* __restrict__ s, const float* __restrict__ bw,
    const float* __restrict__ cw, unsigned short* __restrict__ sb,
    unsigned short* __restrict__ bwb, unsigned short* __restrict__ cwb) {
  long long f = ((long long)blockIdx.x * 256 + threadIdx.x) * 8;
  const float* src;
  unsigned short* dst;
  long long idx;
  if (f < CVT_SN) { src = s; dst = sb; idx = f; }
  else if (f < CVT_SN + CVT_BN) { src = bw; dst = bwb; idx = f - CVT_SN; }
  else { src = cw; dst = cwb; idx = f - CVT_SN - CVT_BN; }
  float4 a = *reinterpret_cast<const float4*>(src + idx);
  float4 b = *reinterpret_cast<const float4*>(src + idx + 4);
  ushort4 lo, hi;
  lo.x = f2bf(a.x); lo.y = f2bf(a.y); lo.z = f2bf(a.z); lo.w = f2bf(a.w);
  hi.x = f2bf(b.x); hi.y = f2bf(b.y); hi.z = f2bf(b.z); hi.w = f2bf(b.w);
  *reinterpret_cast<ushort4*>(dst + idx) = lo;
  *reinterpret_cast<ushort4*>(dst + idx + 4) = hi;
}

// -------------------- shared GEMM1 compute (r4/r7 proven) ------------------
__device__ __forceinline__ void g1_compute(
    const char* bA, const char* bB, f32x4 (&acc)[4][4],
    int wm, int wn, int l15, int g) {
  bf16x8 af[4][2], bfv[4][2];
#pragma unroll
  for (int kk = 0; kk < 2; ++kk) {
    int slotsw = ((kk * 4 + g) ^ (l15 & 7)) * 16;
#pragma unroll
    for (int f = 0; f < 4; ++f) {
      af[f][kk] = *reinterpret_cast<const bf16x8*>(bA + (wm + f * 16 + l15) * 128 + slotsw);
      bfv[f][kk] = *reinterpret_cast<const bf16x8*>(bB + (wn + f * 16 + l15) * 128 + slotsw);
    }
  }
#pragma unroll
  for (int kk = 0; kk < 2; ++kk)
#pragma unroll
    for (int i = 0; i < 4; ++i)
#pragma unroll
      for (int j = 0; j < 4; ++j)
        acc[i][j] = __builtin_amdgcn_mfma_f32_16x16x32_bf16(
            bfv[j][kk], af[i][kk], acc[i][j], 0, 0, 0);
}

// ---- K1 tier-1: b = states@B_w^T+B_b -> bbuf8 (fp8), A reg-staged ----
// A: raw fp32 states, coalesced float4 loads (per-lane m2-permuted addr),
// v_cvt_pk_bf16_f32, swizzled ds_write_b64 (write-swz == read-swz, rule #21).
// B: bwb via glds (pre-swizzled source). Counted vmcnt(12) (B(t) landed).
__global__ __launch_bounds__(256) void k_gemm1p_f(
    const float* __restrict__ states, const unsigned short* __restrict__ bwb,
    const float* __restrict__ Bb, const float* __restrict__ A_log,
    unsigned char* __restrict__ bout8, float* __restrict__ Sb) {
  __shared__ char lds[65536];  // dbuf: [A0|B0|A1|B1] 16K each; epi reuses
  const int tid = threadIdx.x;
  const int wave = tid >> 6, lane = tid & 63;
  const int l15 = lane & 15, g = lane >> 4;
  const int bx = blockIdx.x;
  const int swzb = (bx & 7) * 512 + (bx >> 3);  // bijective XCD swizzle
  const int mt = swzb >> 3, nt = swzb & 7;
  const int m0 = mt * 128, n0 = nt * 128;  // m0 = m2-row base (batch-major)
  const int bb2 = mt >> 4;                 // batch of this tile
  const int c0t = (mt & 15) * 8;           // global t-chunk base
  const int wm = (wave >> 1) * 64, wn = (wave & 1) * 64;
  const int srow = lane >> 3;
  const int swslot = (lane & 7) ^ srow;
  // A reg-staging geometry: thread covers rows i*16+(tid>>4), 16B col (tid&15)
  const int t15 = tid & 15;
  const int rbase8 = tid >> 4;
  const size_t aBase =
      ((size_t)(((mt & 15) * 128 + rbase8) * 32 + bb2)) * 256 + t15 * 4;

#define A_LOAD(tile, av)                                                      \
  _Pragma("unroll")                                                           \
  for (int i = 0; i < 8; ++i)                                                 \
    av[i] = *reinterpret_cast<const float4*>(states + aBase +                 \
                                             (size_t)i * 131072 + (tile) * 64);

#define A_CVT_WRITE(buf, av)                                                  \
  {                                                                           \
    char* dA_ = lds + (buf) * 32768;                                          \
    _Pragma("unroll")                                                         \
    for (int i = 0; i < 8; ++i) {                                             \
      int row_ = i * 16 + rbase8;                                             \
      unsigned int r0_ = cvt_pk_bf16(av[i].x, av[i].y);                       \
      unsigned int r1_ = cvt_pk_bf16(av[i].z, av[i].w);                       \
      int off_ = row_ * 128 + (((t15 >> 1) ^ (row_ & 7)) << 4) + (t15 & 1) * 8;\
      uint2 o_ = {r0_, r1_};                                                  \
      *reinterpret_cast<uint2*>(dA_ + off_) = o_;                             \
    }                                                                         \
  }

#define B_GLDS(tile, buf)                                                     \
  {                                                                           \
    char* dB_ = lds + (buf) * 32768 + 16384;                                  \
    const int k0b_ = (tile) * 128;                                            \
    _Pragma("unroll")                                                         \
    for (int p = 0; p < 4; ++p) {                                             \
      int chunk = wave * 4 + p;                                               \
      GLDS16((const char*)bwb + ((size_t)(n0 + chunk * 8 + srow) * SDIM) * 2 +\
                 k0b_ + swslot * 16,                                          \
             dB_ + chunk * 1024);                                             \
    }                                                                         \
  }

  f32x4 acc[4][4];
#pragma unroll
  for (int i = 0; i < 4; i++)
#pragma unroll
    for (int j = 0; j < 4; j++) acc[i][j] = (f32x4){0.f, 0.f, 0.f, 0.f};

  float4 av[8];
  // prologue: stage tile 0 (A loads first so cvt's reg-wait keeps B in flight)
  A_LOAD(0, av);
  B_GLDS(0, 0);
  A_CVT_WRITE(0, av);
  for (int t = 0; t < 3; ++t) {
    const int cur = t & 1;
    A_LOAD(t + 1, av);
    B_GLDS(t + 1, cur ^ 1);
    asm volatile("s_waitcnt vmcnt(12)" ::: "memory");  // B(t) landed
    asm volatile("s_waitcnt lgkmcnt(0)" ::: "memory"); // A(t) writes done
    __builtin_amdgcn_s_barrier();
    __builtin_amdgcn_sched_barrier(0);
    g1_compute(lds + cur * 32768, lds + cur * 32768 + 16384, acc, wm, wn, l15, g);
    __builtin_amdgcn_s_barrier();
    __builtin_amdgcn_sched_barrier(0);
    A_CVT_WRITE(cur ^ 1, av);
  }
  asm volatile("s_waitcnt vmcnt(0)" ::: "memory");
  asm volatile("s_waitcnt lgkmcnt(0)" ::: "memory");
  __builtin_amdgcn_s_barrier();
  __builtin_amdgcn_sched_barrier(0);
  g1_compute(lds + 32768, lds + 32768 + 16384, acc, wm, wn, l15, g);
  __builtin_amdgcn_s_barrier();
  __builtin_amdgcn_sched_barrier(0);

  // epilogue part 1: bias + pack, per-wave LDS transpose (r7 verbatim)
  char* wb = lds + wave * 9216;
#pragma unroll
  for (int j = 0; j < 4; ++j) {
    float4 bb = *reinterpret_cast<const float4*>(Bb + n0 + wn + j * 16 + g * 4);
#pragma unroll
    for (int i = 0; i < 4; ++i) {
      ushort4 w;
      w.x = f2bf(acc[i][j][0] + bb.x);
      w.y = f2bf(acc[i][j][1] + bb.y);
      w.z = f2bf(acc[i][j][2] + bb.z);
      w.w = f2bf(acc[i][j][3] + bb.w);
      *reinterpret_cast<ushort4*>(wb + (i * 16 + l15) * 144 + j * 32 + g * 8) = w;
    }
  }
  const int h8 = lane & 7;
  const int lr = lane >> 3;
  // epilogue part 2a: fp8 pack + coalesced global store (8B/lane)
#pragma unroll
  for (int tt = 0; tt < 8; ++tt) {
    int ml = lr + tt * 8;
    int4 v = *reinterpret_cast<const int4*>(wb + ml * 144 + h8 * 16);
    unsigned int u[4] = {(unsigned)v.x, (unsigned)v.y, (unsigned)v.z,
                         (unsigned)v.w};
    float f[8];
#pragma unroll
    for (int e = 0; e < 8; ++e) {
      unsigned int bits = (e & 1) ? (u[e >> 1] & 0xFFFF0000u) : (u[e >> 1] << 16);
      f[e] = __uint_as_float(bits);
    }
    int d0 = __builtin_amdgcn_cvt_pk_fp8_f32(f[0], f[1], 0, 0);
    d0 = __builtin_amdgcn_cvt_pk_fp8_f32(f[2], f[3], d0, 1);
    int d1 = __builtin_amdgcn_cvt_pk_fp8_f32(f[4], f[5], 0, 0);
    d1 = __builtin_amdgcn_cvt_pk_fp8_f32(f[6], f[7], d1, 1);
    int2 o = {d0, d1};
    *reinterpret_cast<int2*>(bout8 + (size_t)(m0 + wm + ml) * HID + n0 + wn +
                             h8 * 8) = o;
  }
  // epilogue part 2b: chunk partials via Horner (r12 proven)
  {
    const int c = lr >> 1, half = lr & 1;
    float a1v[8], a8v[8];
    {
      float4 a0 = *reinterpret_cast<const float4*>(A_log + n0 + wn + h8 * 8);
      float4 a1_ = *reinterpret_cast<const float4*>(A_log + n0 + wn + h8 * 8 + 4);
      float al8[8] = {a0.x, a0.y, a0.z, a0.w, a1_.x, a1_.y, a1_.z, a1_.w};
#pragma unroll
      for (int e = 0; e < 8; ++e) {
        a1v[e] = fast_exp2(al8[e] * LOG2E);
        a8v[e] = fast_exp2(al8[e] * (8.0f * LOG2E));
      }
    }
    float s8[8] = {0.f, 0.f, 0.f, 0.f, 0.f, 0.f, 0.f, 0.f};
#pragma unroll
    for (int j = 0; j < 8; ++j) {
      int ml = c * 16 + half * 8 + j;
      int4 v = *reinterpret_cast<const int4*>(wb + ml * 144 + h8 * 16);
      unsigned int u[4] = {(unsigned)v.x, (unsigned)v.y, (unsigned)v.z,
                           (unsigned)v.w};
#pragma unroll
      for (int e = 0; e < 8; ++e) {
        unsigned int bits = (e & 1) ? (u[e >> 1] & 0xFFFF0000u) : (u[e >> 1] << 16);
        s8[e] = fmaf(a1v[e], s8[e], __uint_as_float(bits));
      }
    }
    const float hsel = half ? 1.0f : 0.0f;
#pragma unroll
    for (int e = 0; e < 8; ++e) {
      float scale = hsel + (1.0f - hsel) * a8v[e];  // half?1:a^8, branchless
      s8[e] *= scale;
      s8[e] += __shfl_xor(s8[e], 8);
    }
    if (half == 0) {
      int cg = c0t + (wm >> 4) + c;
      float4 o0 = {s8[0], s8[1], s8[2], s8[3]};
      float4 o1 = {s8[4], s8[5], s8[6], s8[7]};
      float* sp = Sb + (size_t)cg * NCH + bb2 * 1024 + n0 + wn + h8 * 8;
      *reinterpret_cast<float4*>(sp) = o0;
      *reinterpret_cast<float4*>(sp + 4) = o1;
    }
  }
#undef A_LOAD
#undef A_CVT_WRITE
#undef B_GLDS
}

// ---- K1 tier-2: r7 verbatim (glds both operands, permuted bf16 store) ----
#define STAGE1(tile, buf)                                                     \
  {                                                                           \
    const int k0b_ = (tile) * 128;                                            \
    char* dA_ = lds + (buf) * 32768;                                          \
    char* dB_ = lds + 16384 + (buf) * 32768;                                  \
    _Pragma("unroll")                                                         \
    for (int p = 0; p < 4; ++p) {                                             \
      int chunk = wave * 4 + p;                                               \
      GLDS16((const char*)sb + ((size_t)(m0 + chunk * 8 + srow) * SDIM) * 2 + \
                 k0b_ + swslot * 16,                                          \
             dA_ + chunk * 1024);                                             \
      GLDS16((const char*)bwb + ((size_t)(n0 + chunk * 8 + srow) * SDIM) * 2 +\
                 k0b_ + swslot * 16,                                          \
             dB_ + chunk * 1024);                                             \
    }                                                                         \
  }

__global__ __launch_bounds__(256) void k_gemm1p_7(
    const unsigned short* __restrict__ sb, const unsigned short* __restrict__ bwb,
    const float* __restrict__ Bb, unsigned short* __restrict__ bout) {
  __shared__ char lds[65536];
  const int tid = threadIdx.x;
  const int wave = tid >> 6, lane = tid & 63;
  const int l15 = lane & 15, g = lane >> 4;
  const int bx = blockIdx.x;
  const int swzb = (bx & 7) * 512 + (bx >> 3);
  const int m0 = (swzb >> 3) * 128, n0 = (swzb & 7) * 128;
  const int wm = (wave >> 1) * 64, wn = (wave & 1) * 64;
  const int srow = lane >> 3;
  const int swslot = (lane & 7) ^ srow;

  f32x4 acc[4][4];
#pragma unroll
  for (int i = 0; i < 4; i++)
#pragma unroll
    for (int j = 0; j < 4; j++) acc[i][j] = (f32x4){0.f, 0.f, 0.f, 0.f};

  STAGE1(0, 0);
  for (int t = 0; t < 3; ++t) {
    const int cur = t & 1;
    STAGE1(t + 1, cur ^ 1);
    asm volatile("s_waitcnt vmcnt(8)" ::: "memory");
    __builtin_amdgcn_s_barrier();
    __builtin_amdgcn_sched_barrier(0);
    g1_compute(lds + cur * 32768, lds + 16384 + cur * 32768, acc, wm, wn, l15, g);
    __builtin_amdgcn_s_barrier();
    __builtin_amdgcn_sched_barrier(0);
  }
  asm volatile("s_waitcnt vmcnt(0)" ::: "memory");
  __builtin_amdgcn_s_barrier();
  __builtin_amdgcn_sched_barrier(0);
  g1_compute(lds + 32768, lds + 16384 + 32768, acc, wm, wn, l15, g);
  __builtin_amdgcn_s_barrier();
  __builtin_amdgcn_sched_barrier(0);

  char* wb = lds + wave * 9216;
#pragma unroll
  for (int j = 0; j < 4; ++j) {
    float4 bb = *reinterpret_cast<const float4*>(Bb + n0 + wn + j * 16 + g * 4);
#pragma unroll
    for (int i = 0; i < 4; ++i) {
      ushort4 w;
      w.x = f2bf(acc[i][j][0] + bb.x);
      w.y = f2bf(acc[i][j][1] + bb.y);
      w.z = f2bf(acc[i][j][2] + bb.z);
      w.w = f2bf(acc[i][j][3] + bb.w);
      *reinterpret_cast<ushort4*>(wb + (i * 16 + l15) * 144 + j * 32 + g * 8) = w;
    }
  }
#pragma unroll
  for (int tt = 0; tt < 8; ++tt) {
    int ml = (lane >> 3) + tt * 8;
    int4 v = *reinterpret_cast<const int4*>(wb + ml * 144 + (lane & 7) * 16);
    int m = m0 + wm + ml;  // m = t*32 + batch
    size_t dst = ((size_t)(m & 31) * 2048 + (size_t)(m >> 5)) * HID +
                 n0 + wn + (lane & 7) * 8;
    *reinterpret_cast<int4*>(bout + dst) = v;
  }
}

// ------------- K2a (tier-2 only): per-chunk partial scan sums -----------
__global__ __launch_bounds__(256) void k_scan_partial(
    const unsigned short* __restrict__ b2, const float* __restrict__ A_log,
    float* __restrict__ Sbuf) {
  int gid = blockIdx.x * 256 + threadIdx.x;
  int ch = (gid & 4095) * 8;
  int c = gid >> 12;
  int bb = ch >> 10;
  int hh = ch & 1023;
  float4 al0 = *reinterpret_cast<const float4*>(A_log + hh);
  float4 al1 = *reinterpret_cast<const float4*>(A_log + hh + 4);
  float a[8] = {__expf(al0.x), __expf(al0.y), __expf(al0.z), __expf(al0.w),
                __expf(al1.x), __expf(al1.y), __expf(al1.z), __expf(al1.w)};
  const unsigned short* p = b2 + (size_t)bb * 2097152 + (size_t)c * CHUNK * HID + hh;
  float s[8] = {0.f, 0.f, 0.f, 0.f, 0.f, 0.f, 0.f, 0.f};
#pragma unroll 4
  for (int j = 0; j < CHUNK; ++j) {
    int4 v = *reinterpret_cast<const int4*>(p + (size_t)j * HID);
    unsigned int u[4] = {(unsigned)v.x, (unsigned)v.y, (unsigned)v.z, (unsigned)v.w};
#pragma unroll
    for (int e = 0; e < 4; ++e) {
      s[2 * e]     = fmaf(a[2 * e],     s[2 * e],     __uint_as_float(u[e] << 16));
      s[2 * e + 1] = fmaf(a[2 * e + 1], s[2 * e + 1], __uint_as_float(u[e] & 0xFFFF0000u));
    }
  }
  float4 o0 = {s[0], s[1], s[2], s[3]}, o1 = {s[4], s[5], s[6], s[7]};
  *reinterpret_cast<float4*>(Sbuf + (size_t)c * NCH + ch) = o0;
  *reinterpret_cast<float4*>(Sbuf + (size_t)c * NCH + ch + 4) = o1;
}

// ------------- K2b: carry scan (separate-buffer, tier-2) ----------------
__global__ __launch_bounds__(256) void k_scan_carry(
    const float* __restrict__ Sbuf, const float* __restrict__ A_log,
    float* __restrict__ Cbuf) {
  int ch = blockIdx.x * 256 + threadIdx.x;
  float aL = __expf(A_log[ch & (HID - 1)] * (float)CHUNK);
  float h = 0.f;
  for (int c = 0; c < NCHUNK; ++c) {
    Cbuf[(size_t)c * NCH + ch] = h;
    h = fmaf(aL, h, Sbuf[(size_t)c * NCH + ch]);
  }
}

// ------------- K2b': in-place carry (tier-1): S[c] -> C[c] ----------------
__global__ __launch_bounds__(256) void k_scan_carry_ip(
    float* __restrict__ SC, const float* __restrict__ A_log) {
  int ch = blockIdx.x * 256 + threadIdx.x;
  float aL = __expf(A_log[ch & (HID - 1)] * (float)CHUNK);
  float h = 0.f;
  for (int c = 0; c < NCHUNK; ++c) {
    float tmp = SC[(size_t)c * NCH + ch];
    SC[(size_t)c * NCH + ch] = h;
    h = fmaf(aL, h, tmp);
  }
}

// ---- K3 (templated dtype): scan+tanh + mus GEMM + log-prob ----
template <int FP8>
__global__ __launch_bounds__(256) void k_gemm2f_t(
    const void* __restrict__ b2v, const float* __restrict__ actions,
    const unsigned short* __restrict__ cwb, const float* __restrict__ Cb,
    const float* __restrict__ log_std, const float* __restrict__ A_log,
    const float* __restrict__ Cbuf, float* __restrict__ out) {
  __shared__ char lds[49152];  // 3 bufs x {A(8K)|B(8K)}
  const int tid = threadIdx.x;
  const int wave = tid >> 6, lane = tid & 63;
  const int l15 = lane & 15, g = lane >> 4;
  const int bq = blockIdx.x;
  const int bb = bq >> 5;
  const int t0 = (bq & 31) * 64;
  const int c0 = t0 >> 4;
  const int wm = wave * 16;
  const int srow = lane >> 3;
  const int swslot = (lane & 7) ^ srow;
  const int sh = tid & 63;
  const int tq = tid >> 6;

  const size_t elemBase = (size_t)bb * 2097152 + (size_t)(t0 + tq * 16) * HID;
  const unsigned char* srcB8 = (const unsigned char*)b2v + elemBase;
  const unsigned short* srcB16 = (const unsigned short*)b2v + elemBase;
  const float* cbBase = Cbuf + (size_t)(c0 + tq) * NCH + bb * 1024;

  f32x4 acc[4];
#pragma unroll
  for (int j = 0; j < 4; j++) acc[j] = (f32x4){0.f, 0.f, 0.f, 0.f};

  unsigned short va[16];
  float a_cur, h_cur, a_nxt = 0.f, h_nxt = 0.f;
  {
#pragma unroll
    for (int p = 0; p < 2; ++p) {
      int chunk = wave * 2 + p;
      GLDS16((const char*)cwb + ((size_t)(chunk * 8 + srow)) * 2048 +
                 swslot * 16,
             lds + 8192 + chunk * 1024);
    }
    a_cur = A_log[sh];
    h_cur = cbBase[sh];
#pragma unroll
    for (int j = 0; j < 16; ++j)
      va[j] = FP8 ? (unsigned short)srcB8[(size_t)j * HID + sh]
                  : srcB16[(size_t)j * HID + sh];
  }

#pragma unroll
  for (int kt = 0; kt < 16; ++kt) {
    char* buf = lds + (kt % 3) * 16384;
    {
      float a = fast_exp2(a_cur * LOG2E);
      float hst = h_cur;
#pragma unroll
      for (int j = 0; j < 16; ++j) {
        float bval = FP8 ? __builtin_amdgcn_cvt_f32_fp8((int)va[j], 0)
                         : bf2f(va[j]);
        hst = fmaf(a, hst, bval);
        float e = fast_exp2(hst * (2.0f * LOG2E));
        float tn = fmaf(-2.0f, fast_rcp(e + 1.0f), 1.0f);
        int row = tq * 16 + j;
        *reinterpret_cast<unsigned short*>(
            buf + row * 128 + ((sh * 2) ^ ((row & 7) << 4))) = f2bf(tn);
      }
    }
    if (kt < 15) {
      char* nbuf = lds + ((kt + 1) % 3) * 16384;
#pragma unroll
      for (int p = 0; p < 2; ++p) {
        int chunk = wave * 2 + p;
        GLDS16((const char*)cwb + ((size_t)(chunk * 8 + srow)) * 2048 +
                   (kt + 1) * 128 + swslot * 16,
               nbuf + 8192 + chunk * 1024);
      }
      const int hg2 = (kt + 1) * 64 + sh;
      a_nxt = A_log[hg2];
      h_nxt = cbBase[hg2];
#pragma unroll
      for (int j = 0; j < 16; ++j)
        va[j] = FP8 ? (unsigned short)srcB8[(size_t)j * HID + hg2]
                    : srcB16[(size_t)j * HID + hg2];
    }
    __builtin_amdgcn_sched_barrier(0);
    asm volatile("s_waitcnt vmcnt(20)" ::: "memory");
    asm volatile("s_waitcnt lgkmcnt(0)" ::: "memory");
    __builtin_amdgcn_s_barrier();
    __builtin_amdgcn_sched_barrier(0);
    bf16x8 af[2], bfv[4][2];
#pragma unroll
    for (int kk = 0; kk < 2; ++kk) {
      int slotsw = ((kk * 4 + g) ^ (l15 & 7)) * 16;
      af[kk] = *reinterpret_cast<const bf16x8*>(buf + (wm + l15) * 128 + slotsw);
#pragma unroll
      for (int f = 0; f < 4; ++f)
        bfv[f][kk] = *reinterpret_cast<const bf16x8*>(
            buf + 8192 + (f * 16 + l15) * 128 + slotsw);
    }
#pragma unroll
    for (int kk = 0; kk < 2; ++kk)
#pragma unroll
      for (int j = 0; j < 4; ++j)
        acc[j] = __builtin_amdgcn_mfma_f32_16x16x32_bf16(
            af[kk], bfv[j][kk], acc[j], 0, 0, 0);
    a_cur = a_nxt;
    h_cur = h_nxt;
  }
  float istd[4], cb[4];
#pragma unroll
  for (int j = 0; j < 4; ++j) {
    int n = j * 16 + l15;
    istd[j] = __expf(-log_std[n]);
    cb[j] = Cb[n];
  }
  float sls = 0.f;
  for (int n = 0; n < ADIM; ++n) sls += log_std[n];
  const float cterm = -32.0f * 1.8378770664093453f - sls;
  const int rb = wm + g * 4;
#pragma unroll
  for (int r = 0; r < 4; ++r) {
    int rl = rb + r;
    int mo = (t0 + rl) * 32 + bb;
    float ss = 0.f;
#pragma unroll
    for (int j = 0; j < 4; ++j) {
      int n = j * 16 + l15;
      float mu = acc[j][r] + cb[j];
      float d = (actions[(size_t)mo * ADIM + n] - mu) * istd[j];
      ss = fmaf(d, d, ss);
    }
    ss += __shfl_xor(ss, 1);
    ss += __shfl_xor(ss, 2);
    ss += __shfl_xor(ss, 4);
    ss += __shfl_xor(ss, 8);
    if (l15 == 0) out[mo] = cterm - 0.5f * ss;
  }
}

extern "C" void kernel_launch(void* const* d_in, const int* in_sizes, int n_in,
                              void* d_out, int out_size, void* d_ws, size_t ws_size,
                              hipStream_t stream) {
  const float* states  = (const float*)d_in[0];
  const float* actions = (const float*)d_in[1];
  const float* A_log   = (const float*)d_in[2];
  const float* B_w     = (const float*)d_in[3];
  const float* B_b     = (const float*)d_in[4];
  const float* C_w     = (const float*)d_in[5];
  const float* C_b     = (const float*)d_in[6];
  const float* log_std = (const float*)d_in[7];
  float* out = (float*)d_out;
  char* ws = (char*)d_ws;

  if (ws_size >= WS_NEED2) {
    // tier-1: fp8 bbuf, A reg-staged from raw fp32 states (no states copy)
    unsigned char* bbuf8 = (unsigned char*)ws;
    float* SC = (float*)(ws + WS8_SCB);
    unsigned short* bwb = (unsigned short*)(ws + WS8_BWB);
    unsigned short* cwb = (unsigned short*)(ws + WS8_CWB);
    k_cvt_w<<<160, 256, 0, stream>>>(B_w, C_w, bwb, cwb);
    k_gemm1p_f<<<4096, 256, 0, stream>>>(states, bwb, B_b, A_log, bbuf8, SC);
    k_scan_carry_ip<<<128, 256, 0, stream>>>(SC, A_log);
    k_gemm2f_t<1><<<1024, 256, 0, stream>>>(bbuf8, actions, cwb, C_b, log_std,
                                            A_log, SC, out);
  } else {
    // tier-2: round-7 proven path (bf16 bbuf, full pre-convert)
    unsigned short* bbuf = (unsigned short*)ws;
    unsigned short* stb = (unsigned short*)(ws + WS_STB2);
    float* Sbuf = (float*)(ws + WS_SBUF2);
    float* Cbuf = (float*)(ws + WS_CBUF2);
    unsigned short* bwb = (unsigned short*)(ws + WS_BWB2);
    unsigned short* cwb = (unsigned short*)(ws + WS_CWB2);
    k_cvt<<<8352, 256, 0, stream>>>(states, B_w, C_w, stb, bwb, cwb);
    k_gemm1p_7<<<4096, 256, 0, stream>>>(stb, bwb, B_b, bbuf);
    k_scan_partial<<<2048, 256, 0, stream>>>(bbuf, A_log, Sbuf);
    k_scan_carry<<<128, 256, 0, stream>>>(Sbuf, A_log, Cbuf);
    k_gemm2f_t<0><<<1024, 256, 0, stream>>>(bbuf, actions, cwb, C_b, log_std,
                                            A_log, Cbuf, out);
  }
}

// Round 15
// 114.932 us; speedup vs baseline: 1.0153x; 1.0153x over previous
//
#include <hip/hip_runtime.h>
#include <hip/hip_bf16.h>

typedef __attribute__((ext_vector_type(4))) float f32x4;
typedef __attribute__((ext_vector_type(8))) short bf16x8;

#define SDIM 256
#define HID 1024
#define ADIM 64
#define CHUNK 16
#define NCHUNK 128
#define NCH 32768  // BATCH * HID

// tier-1 (fp8 bbuf): bbuf8 [0,64M); stb [64M,96M); SC [96M,112M); bwb; cwb
#define WS8_STB  67108864ull
#define WS8_SCB  100663296ull
#define WS8_BWB  117440512ull
#define WS8_CWB  117964800ull
#define WS8_NEED 118095872ull
// tier-2 (round-7 proven, bf16 bbuf at 0, stb at 128M)
#define WS_STB2  134217728ull
#define WS_SBUF2 134217728ull
#define WS_CBUF2 150994944ull
#define WS_BWB2  167772160ull
#define WS_CWB2  168296448ull
#define WS_NEED2 168427520ull

__device__ __forceinline__ unsigned short f2bf(float f) {
  unsigned int u = __float_as_uint(f);
  u += 0x7FFF + ((u >> 16) & 1);  // RNE
  return (unsigned short)(u >> 16);
}
__device__ __forceinline__ float bf2f(unsigned short h) {
  return __uint_as_float(((unsigned int)h) << 16);
}
// pure (non-volatile): CSE-able, freely schedulable
__device__ __forceinline__ float fast_exp2(float x) {
  float r;
  asm("v_exp_f32 %0, %1" : "=v"(r) : "v"(x));
  return r;
}
__device__ __forceinline__ float fast_rcp(float x) {
  float r;
  asm("v_rcp_f32 %0, %1" : "=v"(r) : "v"(x));
  return r;
}
// pack 2 fp32 -> 2 bf16 (RNE), single HW instr (T12 primitive)
__device__ __forceinline__ unsigned int cvt_pk_bf16(float lo, float hi) {
  unsigned int r;
  asm("v_cvt_pk_bf16_f32 %0, %1, %2" : "=v"(r) : "v"(lo), "v"(hi));
  return r;
}
#define LOG2E 1.4426950408889634f

#define GLDS16(gp, lp)                                                        \
  __builtin_amdgcn_global_load_lds(                                           \
      (const __attribute__((address_space(1))) unsigned int*)(gp),            \
      (__attribute__((address_space(3))) unsigned int*)(lp), 16, 0, 0)

// ---------------- pre-convert fp32 -> bf16 (states, B_w, C_w) --------------
// perm=1: write states rows in m2-order (batch-major: m2=(m&31)*2048+(m>>5))
#define CVT_SN 16777216
#define CVT_BN 262144
#define CVT_CN 65536
__global__ __launch_bounds__(256) void k_cvt(
    const float* __restrict__ s, const float* __restrict__ bw,
    const float* __restrict__ cw, unsigned short* __restrict__ sb,
    unsigned short* __restrict__ bwb, unsigned short* __restrict__ cwb,
    int perm) {
  long long f = ((long long)blockIdx.x * 256 + threadIdx.x) * 8;
  const float* src;
  unsigned short* dst;
  long long idx, didx;
  if (f < CVT_SN) {
    src = s; dst = sb; idx = f;
    if (perm) {
      long long m = f >> 8, col = f & 255;
      didx = ((m & 31) * 2048 + (m >> 5)) * 256 + col;
    } else didx = f;
  } else if (f < CVT_SN + CVT_BN) {
    src = bw; dst = bwb; idx = f - CVT_SN; didx = idx;
  } else {
    src = cw; dst = cwb; idx = f - CVT_SN - CVT_BN; didx = idx;
  }
  float4 a = *reinterpret_cast<const float4*>(src + idx);
  float4 b = *reinterpret_cast<const float4*>(src + idx + 4);
  ushort4 lo, hi;
  lo.x = f2bf(a.x); lo.y = f2bf(a.y); lo.z = f2bf(a.z); lo.w = f2bf(a.w);
  hi.x = f2bf(b.x); hi.y = f2bf(b.y); hi.z = f2bf(b.z); hi.w = f2bf(b.w);
  *reinterpret_cast<ushort4*>(dst + didx) = lo;
  *reinterpret_cast<ushort4*>(dst + didx + 4) = hi;
}

// -------------------- shared GEMM1 compute (r4/r7 proven) ------------------
__device__ __forceinline__ void g1_compute(
    const char* bA, const char* bB, f32x4 (&acc)[4][4],
    int wm, int wn, int l15, int g) {
  bf16x8 af[4][2], bfv[4][2];
#pragma unroll
  for (int kk = 0; kk < 2; ++kk) {
    int slotsw = ((kk * 4 + g) ^ (l15 & 7)) * 16;
#pragma unroll
    for (int f = 0; f < 4; ++f) {
      af[f][kk] = *reinterpret_cast<const bf16x8*>(bA + (wm + f * 16 + l15) * 128 + slotsw);
      bfv[f][kk] = *reinterpret_cast<const bf16x8*>(bB + (wn + f * 16 + l15) * 128 + slotsw);
    }
  }
#pragma unroll
  for (int kk = 0; kk < 2; ++kk)
#pragma unroll
    for (int i = 0; i < 4; ++i)
#pragma unroll
      for (int j = 0; j < 4; ++j)
        acc[i][j] = __builtin_amdgcn_mfma_f32_16x16x32_bf16(
            bfv[j][kk], af[i][kk], acc[i][j], 0, 0, 0);
}

#define STAGE1(tile, buf)                                                     \
  {                                                                           \
    const int k0b_ = (tile) * 128;                                            \
    char* dA_ = lds + (buf) * 32768;                                          \
    char* dB_ = lds + 16384 + (buf) * 32768;                                  \
    _Pragma("unroll")                                                         \
    for (int p = 0; p < 4; ++p) {                                             \
      int chunk = wave * 4 + p;                                               \
      GLDS16((const char*)sb + ((size_t)(m0 + chunk * 8 + srow) * SDIM) * 2 + \
                 k0b_ + swslot * 16,                                          \
             dA_ + chunk * 1024);                                             \
      GLDS16((const char*)bwb + ((size_t)(n0 + chunk * 8 + srow) * SDIM) * 2 +\
                 k0b_ + swslot * 16,                                          \
             dB_ + chunk * 1024);                                             \
    }                                                                         \
  }

#define G1_PIPELINE()                                                         \
  STAGE1(0, 0);                                                               \
  for (int t = 0; t < 3; ++t) {                                               \
    const int cur = t & 1;                                                    \
    STAGE1(t + 1, cur ^ 1);                                                   \
    asm volatile("s_waitcnt vmcnt(8)" ::: "memory");                          \
    __builtin_amdgcn_s_barrier();                                             \
    __builtin_amdgcn_sched_barrier(0);                                        \
    g1_compute(lds + cur * 32768, lds + 16384 + cur * 32768, acc, wm, wn,     \
               l15, g);                                                       \
    __builtin_amdgcn_s_barrier();                                             \
    __builtin_amdgcn_sched_barrier(0);                                        \
  }                                                                           \
  asm volatile("s_waitcnt vmcnt(0)" ::: "memory");                            \
  __builtin_amdgcn_s_barrier();                                               \
  __builtin_amdgcn_sched_barrier(0);                                          \
  g1_compute(lds + 32768, lds + 16384 + 32768, acc, wm, wn, l15, g);          \
  __builtin_amdgcn_s_barrier();                                               \
  __builtin_amdgcn_sched_barrier(0);

// ---- K1 tier-1: b = states@B_w^T+B_b -> bbuf8[b][t][h] (fp8 e4m3) ----
// r7 staging/MFMA; epilogue emits fp8 b + per-16t chunk partials (Horner,
// computed from the bf16 wb tile BEFORE fp8 pack -> carries stay accurate).
// r15: part-1 bias+convert uses v_cvt_pk_bf16_f32 (2 vals/instr, RNE).
__global__ __launch_bounds__(256) void k_gemm1p_f(
    const unsigned short* __restrict__ sb, const unsigned short* __restrict__ bwb,
    const float* __restrict__ Bb, const float* __restrict__ A_log,
    unsigned char* __restrict__ bout8, float* __restrict__ Sb) {
  __shared__ char lds[65536];
  const int tid = threadIdx.x;
  const int wave = tid >> 6, lane = tid & 63;
  const int l15 = lane & 15, g = lane >> 4;
  const int bx = blockIdx.x;
  const int swzb = (bx & 7) * 512 + (bx >> 3);  // bijective XCD swizzle
  const int mt = swzb >> 3, nt = swzb & 7;
  const int m0 = mt * 128, n0 = nt * 128;  // m0 = m2-row base (batch-major)
  const int bb2 = mt >> 4;                 // batch of this tile
  const int c0t = (mt & 15) * 8;           // global t-chunk base
  const int wm = (wave >> 1) * 64, wn = (wave & 1) * 64;
  const int srow = lane >> 3;
  const int swslot = (lane & 7) ^ srow;

  f32x4 acc[4][4];
#pragma unroll
  for (int i = 0; i < 4; i++)
#pragma unroll
    for (int j = 0; j < 4; j++) acc[i][j] = (f32x4){0.f, 0.f, 0.f, 0.f};

  G1_PIPELINE();

  // epilogue part 1: bias + packed bf16 convert, per-wave LDS transpose
  char* wb = lds + wave * 9216;
#pragma unroll
  for (int j = 0; j < 4; ++j) {
    float4 bb = *reinterpret_cast<const float4*>(Bb + n0 + wn + j * 16 + g * 4);
#pragma unroll
    for (int i = 0; i < 4; ++i) {
      unsigned int r0 = cvt_pk_bf16(acc[i][j][0] + bb.x, acc[i][j][1] + bb.y);
      unsigned int r1 = cvt_pk_bf16(acc[i][j][2] + bb.z, acc[i][j][3] + bb.w);
      uint2 o = {r0, r1};
      *reinterpret_cast<uint2*>(wb + (i * 16 + l15) * 144 + j * 32 + g * 8) = o;
    }
  }
  const int h8 = lane & 7;
  const int lr = lane >> 3;
  // epilogue part 2a: fp8 pack + coalesced global store (8B/lane)
#pragma unroll
  for (int tt = 0; tt < 8; ++tt) {
    int ml = lr + tt * 8;
    int4 v = *reinterpret_cast<const int4*>(wb + ml * 144 + h8 * 16);
    unsigned int u[4] = {(unsigned)v.x, (unsigned)v.y, (unsigned)v.z,
                         (unsigned)v.w};
    float f[8];
#pragma unroll
    for (int e = 0; e < 8; ++e) {
      unsigned int bits = (e & 1) ? (u[e >> 1] & 0xFFFF0000u) : (u[e >> 1] << 16);
      f[e] = __uint_as_float(bits);
    }
    int d0 = __builtin_amdgcn_cvt_pk_fp8_f32(f[0], f[1], 0, 0);
    d0 = __builtin_amdgcn_cvt_pk_fp8_f32(f[2], f[3], d0, 1);
    int d1 = __builtin_amdgcn_cvt_pk_fp8_f32(f[4], f[5], 0, 0);
    d1 = __builtin_amdgcn_cvt_pk_fp8_f32(f[6], f[7], d1, 1);
    int2 o = {d0, d1};
    *reinterpret_cast<int2*>(bout8 + (size_t)(m0 + wm + ml) * HID + n0 + wn +
                             h8 * 8) = o;
  }
  // epilogue part 2b: chunk partials via Horner (bf16-accurate; r12 proven)
  {
    const int c = lr >> 1, half = lr & 1;
    float a1v[8], a8v[8];
    {
      float4 a0 = *reinterpret_cast<const float4*>(A_log + n0 + wn + h8 * 8);
      float4 a1_ = *reinterpret_cast<const float4*>(A_log + n0 + wn + h8 * 8 + 4);
      float al8[8] = {a0.x, a0.y, a0.z, a0.w, a1_.x, a1_.y, a1_.z, a1_.w};
#pragma unroll
      for (int e = 0; e < 8; ++e) {
        a1v[e] = fast_exp2(al8[e] * LOG2E);
        a8v[e] = fast_exp2(al8[e] * (8.0f * LOG2E));
      }
    }
    float s8[8] = {0.f, 0.f, 0.f, 0.f, 0.f, 0.f, 0.f, 0.f};
#pragma unroll
    for (int j = 0; j < 8; ++j) {
      int ml = c * 16 + half * 8 + j;
      int4 v = *reinterpret_cast<const int4*>(wb + ml * 144 + h8 * 16);
      unsigned int u[4] = {(unsigned)v.x, (unsigned)v.y, (unsigned)v.z,
                           (unsigned)v.w};
#pragma unroll
      for (int e = 0; e < 8; ++e) {
        unsigned int bits = (e & 1) ? (u[e >> 1] & 0xFFFF0000u) : (u[e >> 1] << 16);
        s8[e] = fmaf(a1v[e], s8[e], __uint_as_float(bits));
      }
    }
    const float hsel = half ? 1.0f : 0.0f;
#pragma unroll
    for (int e = 0; e < 8; ++e) {
      float scale = hsel + (1.0f - hsel) * a8v[e];  // half?1:a^8, branchless
      s8[e] *= scale;
      s8[e] += __shfl_xor(s8[e], 8);
    }
    if (half == 0) {
      int cg = c0t + (wm >> 4) + c;
      float4 o0 = {s8[0], s8[1], s8[2], s8[3]};
      float4 o1 = {s8[4], s8[5], s8[6], s8[7]};
      float* sp = Sb + (size_t)cg * NCH + bb2 * 1024 + n0 + wn + h8 * 8;
      *reinterpret_cast<float4*>(sp) = o0;
      *reinterpret_cast<float4*>(sp + 4) = o1;
    }
  }
}

// ---- K1 tier-2: r7 verbatim (m-order tiles, permuted bf16 store) ----
__global__ __launch_bounds__(256) void k_gemm1p_7(
    const unsigned short* __restrict__ sb, const unsigned short* __restrict__ bwb,
    const float* __restrict__ Bb, unsigned short* __restrict__ bout) {
  __shared__ char lds[65536];
  const int tid = threadIdx.x;
  const int wave = tid >> 6, lane = tid & 63;
  const int l15 = lane & 15, g = lane >> 4;
  const int bx = blockIdx.x;
  const int swzb = (bx & 7) * 512 + (bx >> 3);
  const int m0 = (swzb >> 3) * 128, n0 = (swzb & 7) * 128;
  const int wm = (wave >> 1) * 64, wn = (wave & 1) * 64;
  const int srow = lane >> 3;
  const int swslot = (lane & 7) ^ srow;

  f32x4 acc[4][4];
#pragma unroll
  for (int i = 0; i < 4; i++)
#pragma unroll
    for (int j = 0; j < 4; j++) acc[i][j] = (f32x4){0.f, 0.f, 0.f, 0.f};

  G1_PIPELINE();

  char* wb = lds + wave * 9216;
#pragma unroll
  for (int j = 0; j < 4; ++j) {
    float4 bb = *reinterpret_cast<const float4*>(Bb + n0 + wn + j * 16 + g * 4);
#pragma unroll
    for (int i = 0; i < 4; ++i) {
      ushort4 w;
      w.x = f2bf(acc[i][j][0] + bb.x);
      w.y = f2bf(acc[i][j][1] + bb.y);
      w.z = f2bf(acc[i][j][2] + bb.z);
      w.w = f2bf(acc[i][j][3] + bb.w);
      *reinterpret_cast<ushort4*>(wb + (i * 16 + l15) * 144 + j * 32 + g * 8) = w;
    }
  }
#pragma unroll
  for (int tt = 0; tt < 8; ++tt) {
    int ml = (lane >> 3) + tt * 8;
    int4 v = *reinterpret_cast<const int4*>(wb + ml * 144 + (lane & 7) * 16);
    int m = m0 + wm + ml;  // m = t*32 + batch
    size_t dst = ((size_t)(m & 31) * 2048 + (size_t)(m >> 5)) * HID +
                 n0 + wn + (lane & 7) * 8;
    *reinterpret_cast<int4*>(bout + dst) = v;
  }
}

// ------------- K2a (tier-2 only): per-chunk partial scan sums -----------
__global__ __launch_bounds__(256) void k_scan_partial(
    const unsigned short* __restrict__ b2, const float* __restrict__ A_log,
    float* __restrict__ Sbuf) {
  int gid = blockIdx.x * 256 + threadIdx.x;
  int ch = (gid & 4095) * 8;
  int c = gid >> 12;
  int bb = ch >> 10;
  int hh = ch & 1023;
  float4 al0 = *reinterpret_cast<const float4*>(A_log + hh);
  float4 al1 = *reinterpret_cast<const float4*>(A_log + hh + 4);
  float a[8] = {__expf(al0.x), __expf(al0.y), __expf(al0.z), __expf(al0.w),
                __expf(al1.x), __expf(al1.y), __expf(al1.z), __expf(al1.w)};
  const unsigned short* p = b2 + (size_t)bb * 2097152 + (size_t)c * CHUNK * HID + hh;
  float s[8] = {0.f, 0.f, 0.f, 0.f, 0.f, 0.f, 0.f, 0.f};
#pragma unroll 4
  for (int j = 0; j < CHUNK; ++j) {
    int4 v = *reinterpret_cast<const int4*>(p + (size_t)j * HID);
    unsigned int u[4] = {(unsigned)v.x, (unsigned)v.y, (unsigned)v.z, (unsigned)v.w};
#pragma unroll
    for (int e = 0; e < 4; ++e) {
      s[2 * e]     = fmaf(a[2 * e],     s[2 * e],     __uint_as_float(u[e] << 16));
      s[2 * e + 1] = fmaf(a[2 * e + 1], s[2 * e + 1], __uint_as_float(u[e] & 0xFFFF0000u));
    }
  }
  float4 o0 = {s[0], s[1], s[2], s[3]}, o1 = {s[4], s[5], s[6], s[7]};
  *reinterpret_cast<float4*>(Sbuf + (size_t)c * NCH + ch) = o0;
  *reinterpret_cast<float4*>(Sbuf + (size_t)c * NCH + ch + 4) = o1;
}

// ------------- K2b: carry scan (separate-buffer, tier-2) ----------------
__global__ __launch_bounds__(256) void k_scan_carry(
    const float* __restrict__ Sbuf, const float* __restrict__ A_log,
    float* __restrict__ Cbuf) {
  int ch = blockIdx.x * 256 + threadIdx.x;
  float aL = __expf(A_log[ch & (HID - 1)] * (float)CHUNK);
  float h = 0.f;
  for (int c = 0; c < NCHUNK; ++c) {
    Cbuf[(size_t)c * NCH + ch] = h;
    h = fmaf(aL, h, Sbuf[(size_t)c * NCH + ch]);
  }
}

// ------------- K2b': in-place carry (tier-1): S[c] -> C[c] ----------------
__global__ __launch_bounds__(256) void k_scan_carry_ip(
    float* __restrict__ SC, const float* __restrict__ A_log) {
  int ch = blockIdx.x * 256 + threadIdx.x;
  float aL = __expf(A_log[ch & (HID - 1)] * (float)CHUNK);
  float h = 0.f;
  for (int c = 0; c < NCHUNK; ++c) {
    float tmp = SC[(size_t)c * NCH + ch];
    SC[(size_t)c * NCH + ch] = h;
    h = fmaf(aL, h, tmp);
  }
}

// ---- K3 (templated dtype): scan+tanh + mus GEMM + log-prob ----
template <int FP8>
__global__ __launch_bounds__(256) void k_gemm2f_t(
    const void* __restrict__ b2v, const float* __restrict__ actions,
    const unsigned short* __restrict__ cwb, const float* __restrict__ Cb,
    const float* __restrict__ log_std, const float* __restrict__ A_log,
    const float* __restrict__ Cbuf, float* __restrict__ out) {
  __shared__ char lds[49152];  // 3 bufs x {A(8K)|B(8K)}
  const int tid = threadIdx.x;
  const int wave = tid >> 6, lane = tid & 63;
  const int l15 = lane & 15, g = lane >> 4;
  const int bq = blockIdx.x;
  const int bb = bq >> 5;
  const int t0 = (bq & 31) * 64;
  const int c0 = t0 >> 4;
  const int wm = wave * 16;
  const int srow = lane >> 3;
  const int swslot = (lane & 7) ^ srow;
  const int sh = tid & 63;
  const int tq = tid >> 6;

  const size_t elemBase = (size_t)bb * 2097152 + (size_t)(t0 + tq * 16) * HID;
  const unsigned char* srcB8 = (const unsigned char*)b2v + elemBase;
  const unsigned short* srcB16 = (const unsigned short*)b2v + elemBase;
  const float* cbBase = Cbuf + (size_t)(c0 + tq) * NCH + bb * 1024;

  f32x4 acc[4];
#pragma unroll
  for (int j = 0; j < 4; j++) acc[j] = (f32x4){0.f, 0.f, 0.f, 0.f};

  unsigned short va[16];
  float a_cur, h_cur, a_nxt = 0.f, h_nxt = 0.f;
  {
#pragma unroll
    for (int p = 0; p < 2; ++p) {
      int chunk = wave * 2 + p;
      GLDS16((const char*)cwb + ((size_t)(chunk * 8 + srow)) * 2048 +
                 swslot * 16,
             lds + 8192 + chunk * 1024);
    }
    a_cur = A_log[sh];
    h_cur = cbBase[sh];
#pragma unroll
    for (int j = 0; j < 16; ++j)
      va[j] = FP8 ? (unsigned short)srcB8[(size_t)j * HID + sh]
                  : srcB16[(size_t)j * HID + sh];
  }

#pragma unroll
  for (int kt = 0; kt < 16; ++kt) {
    char* buf = lds + (kt % 3) * 16384;
    {
      float a = fast_exp2(a_cur * LOG2E);
      float hst = h_cur;
#pragma unroll
      for (int j = 0; j < 16; ++j) {
        float bval = FP8 ? __builtin_amdgcn_cvt_f32_fp8((int)va[j], 0)
                         : bf2f(va[j]);
        hst = fmaf(a, hst, bval);
        float e = fast_exp2(hst * (2.0f * LOG2E));
        float tn = fmaf(-2.0f, fast_rcp(e + 1.0f), 1.0f);
        int row = tq * 16 + j;
        *reinterpret_cast<unsigned short*>(
            buf + row * 128 + ((sh * 2) ^ ((row & 7) << 4))) = f2bf(tn);
      }
    }
    if (kt < 15) {
      char* nbuf = lds + ((kt + 1) % 3) * 16384;
#pragma unroll
      for (int p = 0; p < 2; ++p) {
        int chunk = wave * 2 + p;
        GLDS16((const char*)cwb + ((size_t)(chunk * 8 + srow)) * 2048 +
                   (kt + 1) * 128 + swslot * 16,
               nbuf + 8192 + chunk * 1024);
      }
      const int hg2 = (kt + 1) * 64 + sh;
      a_nxt = A_log[hg2];
      h_nxt = cbBase[hg2];
#pragma unroll
      for (int j = 0; j < 16; ++j)
        va[j] = FP8 ? (unsigned short)srcB8[(size_t)j * HID + hg2]
                    : srcB16[(size_t)j * HID + hg2];
    }
    __builtin_amdgcn_sched_barrier(0);
    asm volatile("s_waitcnt vmcnt(20)" ::: "memory");
    asm volatile("s_waitcnt lgkmcnt(0)" ::: "memory");
    __builtin_amdgcn_s_barrier();
    __builtin_amdgcn_sched_barrier(0);
    bf16x8 af[2], bfv[4][2];
#pragma unroll
    for (int kk = 0; kk < 2; ++kk) {
      int slotsw = ((kk * 4 + g) ^ (l15 & 7)) * 16;
      af[kk] = *reinterpret_cast<const bf16x8*>(buf + (wm + l15) * 128 + slotsw);
#pragma unroll
      for (int f = 0; f < 4; ++f)
        bfv[f][kk] = *reinterpret_cast<const bf16x8*>(
            buf + 8192 + (f * 16 + l15) * 128 + slotsw);
    }
#pragma unroll
    for (int kk = 0; kk < 2; ++kk)
#pragma unroll
      for (int j = 0; j < 4; ++j)
        acc[j] = __builtin_amdgcn_mfma_f32_16x16x32_bf16(
            af[kk], bfv[j][kk], acc[j], 0, 0, 0);
    a_cur = a_nxt;
    h_cur = h_nxt;
  }
  float istd[4], cb[4];
#pragma unroll
  for (int j = 0; j < 4; ++j) {
    int n = j * 16 + l15;
    istd[j] = __expf(-log_std[n]);
    cb[j] = Cb[n];
  }
  float sls = 0.f;
  for (int n = 0; n < ADIM; ++n) sls += log_std[n];
  const float cterm = -32.0f * 1.8378770664093453f - sls;
  const int rb = wm + g * 4;
#pragma unroll
  for (int r = 0; r < 4; ++r) {
    int rl = rb + r;
    int mo = (t0 + rl) * 32 + bb;
    float ss = 0.f;
#pragma unroll
    for (int j = 0; j < 4; ++j) {
      int n = j * 16 + l15;
      float mu = acc[j][r] + cb[j];
      float d = (actions[(size_t)mo * ADIM + n] - mu) * istd[j];
      ss = fmaf(d, d, ss);
    }
    ss += __shfl_xor(ss, 1);
    ss += __shfl_xor(ss, 2);
    ss += __shfl_xor(ss, 4);
    ss += __shfl_xor(ss, 8);
    if (l15 == 0) out[mo] = cterm - 0.5f * ss;
  }
}

extern "C" void kernel_launch(void* const* d_in, const int* in_sizes, int n_in,
                              void* d_out, int out_size, void* d_ws, size_t ws_size,
                              hipStream_t stream) {
  const float* states  = (const float*)d_in[0];
  const float* actions = (const float*)d_in[1];
  const float* A_log   = (const float*)d_in[2];
  const float* B_w     = (const float*)d_in[3];
  const float* B_b     = (const float*)d_in[4];
  const float* C_w     = (const float*)d_in[5];
  const float* C_b     = (const float*)d_in[6];
  const float* log_std = (const float*)d_in[7];
  float* out = (float*)d_out;
  char* ws = (char*)d_ws;

  if (ws_size >= WS8_NEED) {
    // tier-1: fp8 bbuf, fused partials in gemm1p epilogue, in-place carry
    unsigned char* bbuf8 = (unsigned char*)ws;
    unsigned short* stb = (unsigned short*)(ws + WS8_STB);
    float* SC = (float*)(ws + WS8_SCB);
    unsigned short* bwb = (unsigned short*)(ws + WS8_BWB);
    unsigned short* cwb = (unsigned short*)(ws + WS8_CWB);
    k_cvt<<<8352, 256, 0, stream>>>(states, B_w, C_w, stb, bwb, cwb, 1);
    k_gemm1p_f<<<4096, 256, 0, stream>>>(stb, bwb, B_b, A_log, bbuf8, SC);
    k_scan_carry_ip<<<128, 256, 0, stream>>>(SC, A_log);
    k_gemm2f_t<1><<<1024, 256, 0, stream>>>(bbuf8, actions, cwb, C_b, log_std,
                                            A_log, SC, out);
  } else {
    // tier-2: round-7 proven path (bf16 bbuf)
    unsigned short* bbuf = (unsigned short*)ws;
    unsigned short* stb = (unsigned short*)(ws + WS_STB2);
    float* Sbuf = (float*)(ws + WS_SBUF2);
    float* Cbuf = (float*)(ws + WS_CBUF2);
    unsigned short* bwb = (unsigned short*)(ws + WS_BWB2);
    unsigned short* cwb = (unsigned short*)(ws + WS_CWB2);
    k_cvt<<<8352, 256, 0, stream>>>(states, B_w, C_w, stb, bwb, cwb, 0);
    k_gemm1p_7<<<4096, 256, 0, stream>>>(stb, bwb, B_b, bbuf);
    k_scan_partial<<<2048, 256, 0, stream>>>(bbuf, A_log, Sbuf);
    k_scan_carry<<<128, 256, 0, stream>>>(Sbuf, A_log, Cbuf);
    k_gemm2f_t<0><<<1024, 256, 0, stream>>>(bbuf, actions, cwb, C_b, log_std,
                                            A_log, Cbuf, out);
  }
}